// Round 18
// baseline (3433.468 us; speedup 1.0000x reference)
//
#include <hip/hip_runtime.h>
#include <hip/hip_bf16.h>
#include <cstddef>
#include <cstdint>

#define BB 64
#define HH 32
#define WW_ 32
#define CC 96
#define WS 8
#define NH 6
#define NL 4
#define ND 6
#define T_TOK (BB*HH*WW_)      // 65536 tokens
#define TC ((size_t)T_TOK*CC)  // 6291456 floats

typedef long long ll;
typedef __attribute__((ext_vector_type(8))) short short8;
typedef __attribute__((ext_vector_type(4))) float f32x4;
typedef __attribute__((ext_vector_type(4))) unsigned short ushort4v;

// Harness-named kernel symbol.
__global__ void JNetSwinIR_41034117546277_kernel() {}

// f32 -> bf16 RNE via the compiler's native conversion (m240: faster than
// hand-written cvt_pk asm; compiler fuses pairs into v_cvt_pk_bf16_f32).
__device__ __forceinline__ unsigned short f2bf(float f) {
  union { __hip_bfloat16 h; unsigned short u; } c;
  c.h = __float2bfloat16(f);
  return c.u;
}
__device__ __forceinline__ unsigned pk2bf(float lo, float hi) {
  return (unsigned)f2bf(lo) | ((unsigned)f2bf(hi) << 16);
}
__device__ __forceinline__ float bf2f(unsigned short h) {
  return __uint_as_float(((unsigned)h) << 16);
}

// ---------------------------------------------------------------- diagnostic fill
__global__ __launch_bounds__(256) void fill_kernel(float* p, float v, int n)
{
  const int idx = blockIdx.x * 256 + threadIdx.x;
  if (idx < n) p[idx] = v;
}

// ---------------------------------------------------------------- weight fp32->bf16 transpose
__global__ __launch_bounds__(256) void wconv_kernel(
    const float* __restrict__ W, unsigned short* __restrict__ Wt, int K, int N)
{
  const int ld = blockIdx.y;
  const int idx = blockIdx.x * 256 + threadIdx.x;
  if (idx >= K * N) return;
  const int k = idx / N, n = idx % N;
  Wt[(size_t)ld * K * N + (size_t)n * K + k] = f2bf(W[(size_t)ld * K * N + idx]);
}

// conv weights [L][3][3][ic][oc] fp32 -> [L][9][oc][ic] bf16
__global__ __launch_bounds__(256) void wconv_conv_kernel(
    const float* __restrict__ W, unsigned short* __restrict__ Wt, int total)
{
  const int idx = blockIdx.x * 256 + threadIdx.x;
  if (idx >= total) return;
  const int l9 = idx / 9216;
  const int rest = idx % 9216;
  const int oc = rest / 96, ic = rest % 96;
  Wt[idx] = f2bf(W[(size_t)(l9 * 96 + ic) * 96 + oc]);
}

// rpb [24][225][6] fp32 -> rpbT [24][6][225] fp32
__global__ __launch_bounds__(256) void rpbt_kernel(
    const float* __restrict__ R, float* __restrict__ Rt)
{
  const int idx = blockIdx.x * 256 + threadIdx.x;
  if (idx >= 24 * 1350) return;
  const int ld = idx / 1350, rest = idx % 1350;
  const int h = rest / 225, ii = rest % 225;
  Rt[idx] = R[(size_t)ld * 1350 + ii * 6 + h];
}

// ---------------------------------------------------------------- LayerNorm fp32 (stem/tail), optional dual write
__global__ __launch_bounds__(256) void ln_fp32_kernel(
    const float* __restrict__ x, const float* __restrict__ gamma,
    const float* __restrict__ beta, float* __restrict__ out, float* out2)
{
  const int wave = threadIdx.x >> 6;
  const int lane = threadIdx.x & 63;
  const int t = blockIdx.x * 4 + wave;
  const float* xp = x + (size_t)t * CC;
  const float v0 = xp[lane];
  const float v1 = (lane < 32) ? xp[64 + lane] : 0.f;
  float s = v0 + v1, s2 = v0 * v0 + v1 * v1;
  #pragma unroll
  for (int off = 32; off; off >>= 1) {
    s  += __shfl_xor(s,  off);
    s2 += __shfl_xor(s2, off);
  }
  const float mean = s * (1.f / 96.f);
  const float var  = s2 * (1.f / 96.f) - mean * mean;
  const float inv  = rsqrtf(var + 1e-5f);
  const float r0 = (v0 - mean) * inv * gamma[lane] + beta[lane];
  const float r1 = (v1 - mean) * inv * gamma[64 + lane] + beta[64 + lane];
  out[(size_t)t * CC + lane] = r0;
  if (lane < 32) out[(size_t)t * CC + 64 + lane] = r1;
  if (out2) {
    out2[(size_t)t * CC + lane] = r0;
    if (lane < 32) out2[(size_t)t * CC + 64 + lane] = r1;
  }
}

// ---------------------------------------------------------------- fully fused swin block
// one block per window, 512 thr = 8 waves. LDS 54016 B -> 3 blocks/CU.
__global__ __launch_bounds__(512) void swin_block_fused(
    float* x, const float* __restrict__ n1s, const float* __restrict__ n1b,
    const unsigned short* __restrict__ wq_ld, const float* __restrict__ qkvb,
    const float* __restrict__ rpbt_ld,
    const unsigned short* __restrict__ wp_ld, const float* __restrict__ projb,
    const float* __restrict__ n2s, const float* __restrict__ n2b,
    const unsigned short* __restrict__ w1_ld, const float* __restrict__ f1b,
    const unsigned short* __restrict__ w2_ld, const float* __restrict__ f2b,
    int shift)
{
  const int widx = blockIdx.x;
  const int tid  = threadIdx.x;
  const int wv   = tid >> 6;      // 0..7
  const int lane = tid & 63;

  // LDS layout (54016 B total):
  //  0      a    [64][104] u16 13312   (LN1/attn-out/LN2-out)
  //  13312  kk   [64][104] u16 (ph2-3) | xacc [64][100] f32 25600 (ph4+, 13312..38912)
  //  26624  vvT  [96][72]  u16 13824 (ph2-3; per-head pbuf overlay in ph3)
  //  40448  qt   [64][104] u16 13312 (ph2-3) | hbuf [64][104] u16 (ph6)
  //  53760  st_s u16[64] 128 ; reg_s i16[64] 128  -> 54016
  __shared__ __attribute__((aligned(16))) char smem[54016];
  auto a    = (unsigned short(*)[104])(smem);
  auto kk   = (unsigned short(*)[104])(smem + 13312);
  auto xacc = (float(*)[100])(smem + 13312);
  unsigned short* vvT = (unsigned short*)(smem + 26624);
  auto qt   = (unsigned short(*)[104])(smem + 40448);
  auto hbuf = (unsigned short(*)[104])(smem + 40448);
  unsigned short* st_s = (unsigned short*)(smem + 53760);
  short*          reg_s = (short*)(smem + 53888);

  if (tid < 64) {
    const int wimg = widx & 15;
    const int h = (wimg >> 2) * 8 + (tid >> 3);
    const int w = (wimg & 3) * 8 + (tid & 7);
    reg_s[tid] = (short)(3 * (h < 24 ? 0 : (h < 28 ? 1 : 2)) +
                             (w < 24 ? 0 : (w < 28 ? 1 : 2)));
    const int b = widx >> 4;
    const int p = (h + shift) & 31, q = (w + shift) & 31;
    st_s[tid] = (unsigned short)((b << 10) + (p << 5) + q);
  }
  __syncthreads();

  const int row = lane & 15;
  const int ko  = (lane >> 4) * 8;
  const int cc  = lane & 15;
  const int cr0 = (lane >> 4) * 4;

  // phase 1: LN1 (8 tokens per wave)
  for (int t = wv; t < 64; t += 8) {
    const float* xp = x + (size_t)st_s[t] * CC;
    const float v0 = xp[lane];
    const float v1 = (lane < 32) ? xp[64 + lane] : 0.f;
    float s = v0 + v1, s2 = v0 * v0 + v1 * v1;
    #pragma unroll
    for (int off = 32; off; off >>= 1) {
      s  += __shfl_xor(s,  off);
      s2 += __shfl_xor(s2, off);
    }
    const float mean = s * (1.f / 96.f);
    const float var  = s2 * (1.f / 96.f) - mean * mean;
    const float inv  = rsqrtf(var + 1e-5f);
    a[t][lane] = f2bf((v0 - mean) * inv * n1s[lane] + n1b[lane]);
    if (lane < 32)
      a[t][64 + lane] = f2bf((v1 - mean) * inv * n1s[64 + lane] + n1b[64 + lane]);
  }
  __syncthreads();

  // phase 2: qkv MFMA — 72 output tiles (4 row x 18 col) over 8 waves
  for (int tt = wv; tt < 72; tt += 8) {
    const int rt = tt / 18, ct = tt % 18;
    const int n0g = ct * 16;
    const unsigned short* bp = wq_ld + (size_t)(n0g + row) * 96 + ko;
    const float bz = qkvb[n0g + cc];
    f32x4 acc = {0.f, 0.f, 0.f, 0.f};
    const unsigned short* ap = &a[rt * 16 + row][ko];
    #pragma unroll
    for (int k0 = 0; k0 < 96; k0 += 32) {
      const short8 af = *(const short8*)(ap + k0);
      const short8 bf = *(const short8*)(bp + k0);
      acc = __builtin_amdgcn_mfma_f32_16x16x32_bf16(af, bf, acc, 0, 0, 0);
    }
    const float v0 = acc[0] + bz, v1 = acc[1] + bz;
    const float v2 = acc[2] + bz, v3 = acc[3] + bz;
    const int tok0 = rt * 16 + cr0;
    if (ct < 6) {
      qt[tok0 + 0][ct * 16 + cc] = f2bf(v0);
      qt[tok0 + 1][ct * 16 + cc] = f2bf(v1);
      qt[tok0 + 2][ct * 16 + cc] = f2bf(v2);
      qt[tok0 + 3][ct * 16 + cc] = f2bf(v3);
    } else if (ct < 12) {
      kk[tok0 + 0][(ct - 6) * 16 + cc] = f2bf(v0);
      kk[tok0 + 1][(ct - 6) * 16 + cc] = f2bf(v1);
      kk[tok0 + 2][(ct - 6) * 16 + cc] = f2bf(v2);
      kk[tok0 + 3][(ct - 6) * 16 + cc] = f2bf(v3);
    } else {
      // vvT rows are tok-contiguous: pack 4 bf16 -> 2 aligned u32 stores
      unsigned* vp = (unsigned*)&vvT[((ct - 12) * 16 + cc) * 72 + tok0];
      vp[0] = pk2bf(v0, v1);
      vp[1] = pk2bf(v2, v3);
    }
  }
  __syncthreads();

  // phase 3: MFMA attention — waves 0..5 (wave = head); 6,7 idle
  if (wv < 6) {
    const int head = wv;
    const int g  = lane >> 4;
    const bool lo = (lane < 32);
    const float* bias_h = rpbt_ld + head * 225;
    unsigned short* pb = vvT + head * (16 * 72);   // overlay own head's vvT rows
    const short8 z8 = {0, 0, 0, 0, 0, 0, 0, 0};
    short8 vf0, vf1;
    {
      const unsigned short* vp = vvT + (size_t)(head * 16 + cc) * 72 + g * 8;
      vf0 = *(const short8*)(vp);
      vf1 = *(const short8*)(vp + 32);
    }
    #pragma unroll
    for (int qtile = 0; qtile < 4; ++qtile) {
      short8 af = z8;
      if (lo) af = *(const short8*)&qt[qtile * 16 + cc][head * 16 + g * 8];
      f32x4 sa[4];
      #pragma unroll
      for (int kt = 0; kt < 4; ++kt) {
        short8 bf = z8;
        if (lo) bf = *(const short8*)&kk[kt * 16 + cc][head * 16 + g * 8];
        const f32x4 zero = {0.f, 0.f, 0.f, 0.f};
        sa[kt] = __builtin_amdgcn_mfma_f32_16x16x32_bf16(af, bf, zero, 0, 0, 0);
      }
      float p[4][4];
      #pragma unroll
      for (int r = 0; r < 4; ++r) {
        const int i = qtile * 16 + g * 4 + r;
        const int ih = i >> 3, iw = i & 7;
        const int ri = reg_s[i];
        float mx = -1e30f;
        #pragma unroll
        for (int kt = 0; kt < 4; ++kt) {
          const int j = kt * 16 + cc;
          const int idx = (ih - (j >> 3) + 7) * 15 + (iw - (j & 7) + 7);
          float v = sa[kt][r] * 0.25f + bias_h[idx];
          if (shift && reg_s[j] != ri) v -= 100.f;
          p[kt][r] = v;
          mx = fmaxf(mx, v);
        }
        mx = fmaxf(mx, __shfl_xor(mx, 1));
        mx = fmaxf(mx, __shfl_xor(mx, 2));
        mx = fmaxf(mx, __shfl_xor(mx, 4));
        mx = fmaxf(mx, __shfl_xor(mx, 8));
        float sum = 0.f;
        #pragma unroll
        for (int kt = 0; kt < 4; ++kt) {
          p[kt][r] = __expf(p[kt][r] - mx);
          sum += p[kt][r];
        }
        sum += __shfl_xor(sum, 1);
        sum += __shfl_xor(sum, 2);
        sum += __shfl_xor(sum, 4);
        sum += __shfl_xor(sum, 8);
        const float is = 1.f / sum;
        #pragma unroll
        for (int kt = 0; kt < 4; ++kt)
          pb[(g * 4 + r) * 72 + kt * 16 + cc] = f2bf(p[kt][r] * is);
      }
      f32x4 oa = {0.f, 0.f, 0.f, 0.f};
      {
        const unsigned short* pp = pb + cc * 72 + g * 8;
        const short8 pf0 = *(const short8*)(pp);
        const short8 pf1 = *(const short8*)(pp + 32);
        oa = __builtin_amdgcn_mfma_f32_16x16x32_bf16(pf0, vf0, oa, 0, 0, 0);
        oa = __builtin_amdgcn_mfma_f32_16x16x32_bf16(pf1, vf1, oa, 0, 0, 0);
      }
      #pragma unroll
      for (int r = 0; r < 4; ++r)
        a[qtile * 16 + g * 4 + r][head * 16 + cc] = f2bf(oa[r]);
    }
  }
  __syncthreads();

  // phase 4: proj MFMA; xacc = x_old + proj + bias — 24 tiles over 8 waves
  for (int tt = wv; tt < 24; tt += 8) {
    const int rt = tt / 6, ct = tt % 6;
    const int n0 = ct * 16;
    const int tok0 = rt * 16 + cr0;
    // hoist x_old loads: overlap global latency with the MFMA chain
    float xo[4];
    #pragma unroll
    for (int r = 0; r < 4; ++r)
      xo[r] = x[(size_t)st_s[tok0 + r] * CC + n0 + cc];
    const unsigned short* bp = wp_ld + (size_t)(n0 + row) * 96 + ko;
    const float bz = projb[n0 + cc];
    f32x4 acc = {0.f, 0.f, 0.f, 0.f};
    const unsigned short* ap = &a[rt * 16 + row][ko];
    #pragma unroll
    for (int k0 = 0; k0 < 96; k0 += 32) {
      const short8 af = *(const short8*)(ap + k0);
      const short8 bf = *(const short8*)(bp + k0);
      acc = __builtin_amdgcn_mfma_f32_16x16x32_bf16(af, bf, acc, 0, 0, 0);
    }
    #pragma unroll
    for (int r = 0; r < 4; ++r)
      xacc[tok0 + r][n0 + cc] = xo[r] + acc[r] + bz;
  }
  __syncthreads();

  // phase 5: LN2 from xacc -> a
  for (int t = wv; t < 64; t += 8) {
    const float v0 = xacc[t][lane];
    const float v1 = (lane < 32) ? xacc[t][64 + lane] : 0.f;
    float s = v0 + v1, s2 = v0 * v0 + v1 * v1;
    #pragma unroll
    for (int off = 32; off; off >>= 1) {
      s  += __shfl_xor(s,  off);
      s2 += __shfl_xor(s2, off);
    }
    const float mean = s * (1.f / 96.f);
    const float var  = s2 * (1.f / 96.f) - mean * mean;
    const float inv  = rsqrtf(var + 1e-5f);
    a[t][lane] = f2bf((v0 - mean) * inv * n2s[lane] + n2b[lane]);
    if (lane < 32)
      a[t][64 + lane] = f2bf((v1 - mean) * inv * n2s[64 + lane] + n2b[64 + lane]);
  }
  __syncthreads();

  // phase 6: MLP in 4 K-passes of 96 hidden cols; fc2 tiles fixed per wave
  f32x4 acc2[3];
  #pragma unroll
  for (int i = 0; i < 3; ++i) acc2[i] = (f32x4){0.f, 0.f, 0.f, 0.f};
  for (int p = 0; p < 4; ++p) {
    for (int tt = wv; tt < 24; tt += 8) {
      const int rt = tt / 6, ct = tt % 6;
      const int n0g = p * 96 + ct * 16;
      const unsigned short* bp = w1_ld + (size_t)(n0g + row) * 96 + ko;
      const float bz = f1b[n0g + cc];
      f32x4 acc = {0.f, 0.f, 0.f, 0.f};
      const unsigned short* ap = &a[rt * 16 + row][ko];
      #pragma unroll
      for (int k0 = 0; k0 < 96; k0 += 32) {
        const short8 af = *(const short8*)(ap + k0);
        const short8 bf = *(const short8*)(bp + k0);
        acc = __builtin_amdgcn_mfma_f32_16x16x32_bf16(af, bf, acc, 0, 0, 0);
      }
      #pragma unroll
      for (int r = 0; r < 4; ++r) {
        float v = acc[r] + bz;
        v = 0.5f * v * (1.f + erff(v * 0.70710678118f));
        hbuf[rt * 16 + cr0 + r][ct * 16 + cc] = f2bf(v);
      }
    }
    __syncthreads();
    #pragma unroll
    for (int i = 0; i < 3; ++i) {
      const int tt2 = wv * 3 + i;
      const int rt = tt2 / 6, ct = tt2 % 6;
      const unsigned short* bp = w2_ld + (size_t)(ct * 16 + row) * 384 + p * 96 + ko;
      const unsigned short* ap = &hbuf[rt * 16 + row][ko];
      #pragma unroll
      for (int k0 = 0; k0 < 96; k0 += 32) {
        const short8 af = *(const short8*)(ap + k0);
        const short8 bf = *(const short8*)(bp + k0);
        acc2[i] = __builtin_amdgcn_mfma_f32_16x16x32_bf16(af, bf, acc2[i], 0, 0, 0);
      }
    }
    __syncthreads();
  }

  // phase 7: final write x = xacc + fc2 + bias
  #pragma unroll
  for (int i = 0; i < 3; ++i) {
    const int tt2 = wv * 3 + i;
    const int rt = tt2 / 6, ct = tt2 % 6;
    const int n0 = ct * 16;
    const float bz = f2b[n0 + cc];
    #pragma unroll
    for (int r = 0; r < 4; ++r) {
      const int tok = rt * 16 + cr0 + r;
      x[(size_t)st_s[tok] * CC + n0 + cc] = xacc[tok][n0 + cc] + acc2[i][r] + bz;
    }
  }
}

// ---------------------------------------------------------------- copy
__global__ __launch_bounds__(256) void copy_kernel(
    float* __restrict__ dst, const float* __restrict__ src)
{
  const int idx = blockIdx.x * 256 + threadIdx.x;
  dst[idx] = src[idx];
}

// ---------------------------------------------------------------- conv 3x3 96->96, MFMA implicit GEMM, optional dual write
__global__ __launch_bounds__(256) void conv96m_kernel(
    const float* __restrict__ x, const unsigned short* __restrict__ wt,
    const float* __restrict__ bias, const float* resid, float* out, float* out2)
{
  const int blk = blockIdx.x;
  const int b = blk >> 4, th = (blk >> 2) & 3, tw = blk & 3;
  const int h0 = th * 8, w0 = tw * 8;
  __shared__ unsigned short patch[100][104];
  for (int idx = threadIdx.x; idx < 100 * 24; idx += 256) {
    const int pp = idx / 24, c4 = (idx % 24) * 4;
    const int ph = pp / 10, pw = pp % 10;
    const int hh = h0 + ph - 1, ww = w0 + pw - 1;
    float4 v = {0.f, 0.f, 0.f, 0.f};
    if ((unsigned)hh < 32u && (unsigned)ww < 32u)
      v = *(const float4*)&x[(((size_t)b * 32 + hh) * 32 + ww) * 96 + c4];
    ushort4v o;
    o.x = f2bf(v.x); o.y = f2bf(v.y); o.z = f2bf(v.z); o.w = f2bf(v.w);
    *(ushort4v*)&patch[pp][c4] = o;
  }
  __syncthreads();
  const int wv = threadIdx.x >> 6, lane = threadIdx.x & 63;
  const int m0 = wv * 16;
  const int arow = lane & 15;
  const int ko  = (lane >> 4) * 8;
  const int px = m0 + arow;
  const int ph_ = px >> 3, pw_ = px & 7;
  f32x4 acc[6];
  #pragma unroll
  for (int i = 0; i < 6; ++i) acc[i] = (f32x4){0.f, 0.f, 0.f, 0.f};
  #pragma unroll
  for (int kh = 0; kh < 3; ++kh)
    #pragma unroll
    for (int kw = 0; kw < 3; ++kw) {
      const unsigned short* wbase = wt + (size_t)(kh * 3 + kw) * 9216;
      const unsigned short* prow = &patch[(ph_ + kh) * 10 + (pw_ + kw)][ko];
      #pragma unroll
      for (int k0 = 0; k0 < 96; k0 += 32) {
        const short8 af = *(const short8*)(prow + k0);
        #pragma unroll
        for (int nt = 0; nt < 6; ++nt) {
          const short8 bf = *(const short8*)(wbase + (size_t)(nt * 16 + arow) * 96 + ko + k0);
          acc[nt] = __builtin_amdgcn_mfma_f32_16x16x32_bf16(af, bf, acc[nt], 0, 0, 0);
        }
      }
    }
  const int cc = lane & 15;
  const int cr0 = (lane >> 4) * 4;
  #pragma unroll
  for (int nt = 0; nt < 6; ++nt) {
    const int oc = nt * 16 + cc;
    const float bz = bias[oc];
    #pragma unroll
    for (int r = 0; r < 4; ++r) {
      const int p = m0 + cr0 + r;
      const int h = p >> 3, w = p & 7;
      const size_t t = (((size_t)b * 32 + h0 + h) * 32 + (w0 + w));
      float v = acc[nt][r] + bz;
      if (resid) v += resid[t * 96 + oc];
      out[t * 96 + oc] = v;
      if (out2) out2[t * 96 + oc] = v;
    }
  }
}

// ---------------------------------------------------------------- conv stem 4->96
__global__ __launch_bounds__(256) void conv_first_kernel(
    const float* __restrict__ es, const float* __restrict__ jp,
    const float* __restrict__ wgt, const float* __restrict__ bias,
    float* __restrict__ xf)
{
  const int idx = blockIdx.x * 256 + threadIdx.x;
  const int oc = idx % 96;
  const int pos = idx / 96;
  const int w = pos % 32, hp = (pos / 32) % 32, b = pos / 1024;
  float acc = bias[oc];
  for (int kh = 0; kh < 3; ++kh) {
    const int hh = hp + kh - 1;
    if ((unsigned)hh >= 32u) continue;
    for (int kw = 0; kw < 3; ++kw) {
      const int ww = w + kw - 1;
      if ((unsigned)ww >= 32u) continue;
      const size_t sp = ((size_t)b * 2 * 32 + hh) * 32 + ww;
      const float i0 = es[sp];
      const float i1 = es[sp + 1024];
      const float i2 = jp[sp];
      const float i3 = jp[sp + 1024];
      const float* wr = wgt + (size_t)((kh * 3 + kw) * 4) * 96 + oc;
      acc = fmaf(i0, wr[0], acc);
      acc = fmaf(i1, wr[96], acc);
      acc = fmaf(i2, wr[192], acc);
      acc = fmaf(i3, wr[288], acc);
    }
  }
  xf[idx] = acc;
}

// ---------------------------------------------------------------- conv tail 96->2
__global__ __launch_bounds__(256) void conv_last_kernel(
    const float* __restrict__ res, const float* __restrict__ wgt,
    const float* __restrict__ bias, float* __restrict__ out)
{
  const int idx = blockIdx.x * 256 + threadIdx.x;
  const int oc = idx % 2;
  const int pos = idx / 2;
  const int w = pos % 32, hp = (pos / 32) % 32, b = pos / 1024;
  float acc = bias[oc];
  for (int kh = 0; kh < 3; ++kh) {
    const int hh = hp + kh - 1;
    if ((unsigned)hh >= 32u) continue;
    for (int kw = 0; kw < 3; ++kw) {
      const int ww = w + kw - 1;
      if ((unsigned)ww >= 32u) continue;
      const float* pr = res + (((size_t)b * 32 + hh) * 32 + ww) * 96;
      const float* wr = wgt + (size_t)((kh * 3 + kw) * 96) * 2 + oc;
      #pragma unroll 8
      for (int ic = 0; ic < 96; ++ic)
        acc = fmaf(pr[ic], wr[ic * 2], acc);
    }
  }
  out[(((size_t)b * 2 + oc) * 32 + hp) * 32 + w] = acc;
}

// ---------------------------------------------------------------- host
extern "C" void kernel_launch(void* const* d_in, const int* in_sizes, int n_in,
                              void* d_out, int out_size, void* d_ws, size_t ws_size,
                              hipStream_t stream)
{
  const int fill_grid = (out_size + 255) / 256;

  if (n_in != 27) {
    fill_kernel<<<fill_grid, 256, 0, stream>>>((float*)d_out, 200.0f + (float)n_in, out_size);
    return;
  }
  static const int expected_sizes[27] = {
    131072, 131072, 3456, 96, 96, 96, 2304, 2304, 663552, 6912,
    221184, 2304, 32400, 2304, 2304, 884736, 9216, 884736, 2304,
    331776, 384, 96, 96, 82944, 96, 1728, 2
  };
  for (int i = 0; i < 27; ++i) {
    if (in_sizes[i] != expected_sizes[i]) {
      fill_kernel<<<fill_grid, 256, 0, stream>>>((float*)d_out, 300.0f + (float)i, out_size);
      return;
    }
  }
  if (out_size != 131072) {
    fill_kernel<<<fill_grid, 256, 0, stream>>>((float*)d_out, 400.0f, out_size);
    return;
  }
  const uintptr_t raw = (uintptr_t)d_ws;
  const uintptr_t alignedp = (raw + 255) & ~(uintptr_t)255;
  const size_t ws_avail_bytes = (ws_size > (alignedp - raw)) ? ws_size - (alignedp - raw) : 0;
  const size_t avail = ws_avail_bytes / 4;   // floats
  const size_t WBUF_F = 1534464 + 32400;     // bf16 weights + rpbT(f32), float units
  if (avail < 2 * TC + WBUF_F) {
    fill_kernel<<<fill_grid, 256, 0, stream>>>((float*)d_out,
        100.0f + (float)(ws_size >> 20), out_size);
    return;
  }
  const bool rot = (avail >= 3 * TC + WBUF_F);   // 3-buffer rotation (no copies)

  const float* es      = (const float*)d_in[0];
  const float* jp      = (const float*)d_in[1];
  const float* cf_w    = (const float*)d_in[2];
  const float* cf_b    = (const float*)d_in[3];
  const float* pe_s    = (const float*)d_in[4];
  const float* pe_b    = (const float*)d_in[5];
  const float* n1_s    = (const float*)d_in[6];
  const float* n1_b    = (const float*)d_in[7];
  const float* qkv_w   = (const float*)d_in[8];
  const float* qkv_b   = (const float*)d_in[9];
  const float* proj_w  = (const float*)d_in[10];
  const float* proj_b  = (const float*)d_in[11];
  const float* rpb     = (const float*)d_in[12];
  const float* n2_s    = (const float*)d_in[13];
  const float* n2_b    = (const float*)d_in[14];
  const float* fc1_w   = (const float*)d_in[15];
  const float* fc1_b   = (const float*)d_in[16];
  const float* fc2_w   = (const float*)d_in[17];
  const float* fc2_b   = (const float*)d_in[18];
  const float* rstb_w  = (const float*)d_in[19];
  const float* rstb_b  = (const float*)d_in[20];
  const float* nf_s    = (const float*)d_in[21];
  const float* nf_b    = (const float*)d_in[22];
  const float* body_w  = (const float*)d_in[23];
  const float* body_b  = (const float*)d_in[24];
  const float* last_w  = (const float*)d_in[25];
  const float* last_b  = (const float*)d_in[26];

  float* base = (float*)alignedp;
  float* x  = base;
  float* r  = base + TC;
  float* sp = rot ? base + 2 * TC : nullptr;
  unsigned short* wq  = (unsigned short*)(base + (rot ? 3 : 2) * TC);
  unsigned short* wpj = wq + 663552;
  unsigned short* w1  = wpj + 221184;
  unsigned short* w2  = w1 + 884736;
  unsigned short* wcr = w2 + 884736;
  unsigned short* wcb = wcr + 331776;
  float* rpbt = (float*)(wcb + 82944);          // [24][6][225] f32

  const int grid_tc = (int)(TC / 256);
  const int grid_lf = T_TOK / 4;
  const int nwin = T_TOK / 64;                       // 1024

  // weight convert+transpose
  wconv_kernel<<<dim3((96 * 288 + 255) / 256, 24), 256, 0, stream>>>(qkv_w, wq, 96, 288);
  wconv_kernel<<<dim3((96 * 96 + 255) / 256, 24), 256, 0, stream>>>(proj_w, wpj, 96, 96);
  wconv_kernel<<<dim3((96 * 384 + 255) / 256, 24), 256, 0, stream>>>(fc1_w, w1, 96, 384);
  wconv_kernel<<<dim3((384 * 96 + 255) / 256, 24), 256, 0, stream>>>(fc2_w, w2, 384, 96);
  wconv_conv_kernel<<<(331776 + 255) / 256, 256, 0, stream>>>(rstb_w, wcr, 331776);
  wconv_conv_kernel<<<(82944 + 255) / 256, 256, 0, stream>>>(body_w, wcb, 82944);
  rpbt_kernel<<<(24 * 1350 + 255) / 256, 256, 0, stream>>>(rpb, rpbt);

  // stem
  conv_first_kernel<<<grid_tc, 256, 0, stream>>>(es, jp, cf_w, cf_b, x);
  ln_fp32_kernel<<<grid_lf, 256, 0, stream>>>(x, pe_s, pe_b, x, rot ? r : nullptr);

  float* xb = x;
  float* rb = r;
  float* sb = sp;
  for (int l = 0; l < NL; ++l) {
    if (!rot) copy_kernel<<<grid_tc, 256, 0, stream>>>(rb, xb);
    for (int d = 0; d < ND; ++d) {
      const int ld = l * ND + d;
      const int shift = (d & 1) ? 4 : 0;
      swin_block_fused<<<nwin, 512, 0, stream>>>(
          xb, n1_s + ld * CC, n1_b + ld * CC,
          wq + (size_t)ld * 288 * 96, qkv_b + (size_t)ld * 288,
          rpbt + (size_t)ld * 1350,
          wpj + (size_t)ld * 96 * 96, proj_b + (size_t)ld * 96,
          n2_s + ld * CC, n2_b + ld * CC,
          w1 + (size_t)ld * 384 * 96, fc1_b + (size_t)ld * 384,
          w2 + (size_t)ld * 96 * 384, fc2_b + (size_t)ld * 96, shift);
    }
    if (rot) {
      conv96m_kernel<<<1024, 256, 0, stream>>>(xb, wcr + (size_t)l * 9 * 9216,
                                               rstb_b + (size_t)l * CC, rb, rb, sb);
      float* t = xb; xb = sb; sb = t;
    } else {
      conv96m_kernel<<<1024, 256, 0, stream>>>(xb, wcr + (size_t)l * 9 * 9216,
                                               rstb_b + (size_t)l * CC, rb, rb, nullptr);
      float* t = xb; xb = rb; rb = t;
    }
  }
  // tail
  ln_fp32_kernel<<<grid_lf, 256, 0, stream>>>(xb, nf_s, nf_b, rb, nullptr);
  conv_first_kernel<<<grid_tc, 256, 0, stream>>>(es, jp, cf_w, cf_b, xb);
  conv96m_kernel<<<1024, 256, 0, stream>>>(rb, wcb, body_b, xb, xb, nullptr);
  conv_last_kernel<<<(BB * 32 * 32 * 2) / 256, 256, 0, stream>>>(xb, last_w, last_b, (float*)d_out);
}

// Round 20
// 3326.615 us; speedup vs baseline: 1.0321x; 1.0321x over previous
//
#include <hip/hip_runtime.h>
#include <hip/hip_bf16.h>
#include <cstddef>
#include <cstdint>

#define BB 64
#define HH 32
#define WW_ 32
#define CC 96
#define WS 8
#define NH 6
#define NL 4
#define ND 6
#define T_TOK (BB*HH*WW_)      // 65536 tokens
#define TC ((size_t)T_TOK*CC)  // 6291456 floats

typedef long long ll;
typedef __attribute__((ext_vector_type(8))) short short8;
typedef __attribute__((ext_vector_type(4))) float f32x4;
typedef __attribute__((ext_vector_type(4))) unsigned short ushort4v;

// Harness-named kernel symbol.
__global__ void JNetSwinIR_41034117546277_kernel() {}

// manual RNE f32->bf16 (measured-best path, R16 = 3.324 ms)
__device__ __forceinline__ unsigned short f2bf(float f) {
  unsigned u = __float_as_uint(f);
  unsigned r = (u + 0x7FFF + ((u >> 16) & 1)) >> 16;
  return (unsigned short)r;
}
__device__ __forceinline__ float bf2f(unsigned short h) {
  return __uint_as_float(((unsigned)h) << 16);
}

// ---------------------------------------------------------------- diagnostic fill
__global__ __launch_bounds__(256) void fill_kernel(float* p, float v, int n)
{
  const int idx = blockIdx.x * 256 + threadIdx.x;
  if (idx < n) p[idx] = v;
}

// ---------------------------------------------------------------- weight fp32->bf16 transpose
__global__ __launch_bounds__(256) void wconv_kernel(
    const float* __restrict__ W, unsigned short* __restrict__ Wt, int K, int N)
{
  const int ld = blockIdx.y;
  const int idx = blockIdx.x * 256 + threadIdx.x;
  if (idx >= K * N) return;
  const int k = idx / N, n = idx % N;
  Wt[(size_t)ld * K * N + (size_t)n * K + k] = f2bf(W[(size_t)ld * K * N + idx]);
}

// conv weights [L][3][3][ic][oc] fp32 -> [L][9][oc][ic] bf16
__global__ __launch_bounds__(256) void wconv_conv_kernel(
    const float* __restrict__ W, unsigned short* __restrict__ Wt, int total)
{
  const int idx = blockIdx.x * 256 + threadIdx.x;
  if (idx >= total) return;
  const int l9 = idx / 9216;
  const int rest = idx % 9216;
  const int oc = rest / 96, ic = rest % 96;
  Wt[idx] = f2bf(W[(size_t)(l9 * 96 + ic) * 96 + oc]);
}

// rpb [24][225][6] fp32 -> rpbT [24][6][225] fp32
__global__ __launch_bounds__(256) void rpbt_kernel(
    const float* __restrict__ R, float* __restrict__ Rt)
{
  const int idx = blockIdx.x * 256 + threadIdx.x;
  if (idx >= 24 * 1350) return;
  const int ld = idx / 1350, rest = idx % 1350;
  const int h = rest / 225, ii = rest % 225;
  Rt[idx] = R[(size_t)ld * 1350 + ii * 6 + h];
}

// ---------------------------------------------------------------- LayerNorm fp32 (stem/tail), optional dual write
__global__ __launch_bounds__(256) void ln_fp32_kernel(
    const float* __restrict__ x, const float* __restrict__ gamma,
    const float* __restrict__ beta, float* __restrict__ out, float* out2)
{
  const int wave = threadIdx.x >> 6;
  const int lane = threadIdx.x & 63;
  const int t = blockIdx.x * 4 + wave;
  const float* xp = x + (size_t)t * CC;
  const float v0 = xp[lane];
  const float v1 = (lane < 32) ? xp[64 + lane] : 0.f;
  float s = v0 + v1, s2 = v0 * v0 + v1 * v1;
  #pragma unroll
  for (int off = 32; off; off >>= 1) {
    s  += __shfl_xor(s,  off);
    s2 += __shfl_xor(s2, off);
  }
  const float mean = s * (1.f / 96.f);
  const float var  = s2 * (1.f / 96.f) - mean * mean;
  const float inv  = rsqrtf(var + 1e-5f);
  const float r0 = (v0 - mean) * inv * gamma[lane] + beta[lane];
  const float r1 = (v1 - mean) * inv * gamma[64 + lane] + beta[64 + lane];
  out[(size_t)t * CC + lane] = r0;
  if (lane < 32) out[(size_t)t * CC + 64 + lane] = r1;
  if (out2) {
    out2[(size_t)t * CC + lane] = r0;
    if (lane < 32) out2[(size_t)t * CC + 64 + lane] = r1;
  }
}

// ---------------------------------------------------------------- fully fused swin block
// one block per window, 512 thr = 8 waves. LDS 54016 B -> 3 blocks/CU.
__global__ __launch_bounds__(512) void swin_block_fused(
    float* x, const float* __restrict__ n1s, const float* __restrict__ n1b,
    const unsigned short* __restrict__ wq_ld, const float* __restrict__ qkvb,
    const float* __restrict__ rpbt_ld,
    const unsigned short* __restrict__ wp_ld, const float* __restrict__ projb,
    const float* __restrict__ n2s, const float* __restrict__ n2b,
    const unsigned short* __restrict__ w1_ld, const float* __restrict__ f1b,
    const unsigned short* __restrict__ w2_ld, const float* __restrict__ f2b,
    int shift)
{
  const int widx = blockIdx.x;
  const int tid  = threadIdx.x;
  const int wv   = tid >> 6;      // 0..7
  const int lane = tid & 63;

  // LDS layout (54016 B total):
  //  0      a    [64][104] u16 13312   (LN1/attn-out/LN2-out)
  //  13312  kk   [64][104] u16 (ph2-3) | xacc [64][100] f32 25600 (ph4+, 13312..38912)
  //  26624  vvT  [96][72]  u16 13824 (ph2-3; per-head pbuf overlay in ph3)
  //  40448  qt   [64][104] u16 13312 (ph2-3) | hbuf [64][104] u16 (ph6)
  //  53760  st_s u16[64] 128 ; reg_s i16[64] 128  -> 54016
  __shared__ __attribute__((aligned(16))) char smem[54016];
  auto a    = (unsigned short(*)[104])(smem);
  auto kk   = (unsigned short(*)[104])(smem + 13312);
  auto xacc = (float(*)[100])(smem + 13312);
  unsigned short* vvT = (unsigned short*)(smem + 26624);
  auto qt   = (unsigned short(*)[104])(smem + 40448);
  auto hbuf = (unsigned short(*)[104])(smem + 40448);
  unsigned short* st_s = (unsigned short*)(smem + 53760);
  short*          reg_s = (short*)(smem + 53888);

  if (tid < 64) {
    const int wimg = widx & 15;
    const int h = (wimg >> 2) * 8 + (tid >> 3);
    const int w = (wimg & 3) * 8 + (tid & 7);
    reg_s[tid] = (short)(3 * (h < 24 ? 0 : (h < 28 ? 1 : 2)) +
                             (w < 24 ? 0 : (w < 28 ? 1 : 2)));
    const int b = widx >> 4;
    const int p = (h + shift) & 31, q = (w + shift) & 31;
    st_s[tid] = (unsigned short)((b << 10) + (p << 5) + q);
  }
  __syncthreads();

  const int row = lane & 15;
  const int ko  = (lane >> 4) * 8;
  const int cc  = lane & 15;
  const int cr0 = (lane >> 4) * 4;

  // phase 1: LN1 (8 tokens per wave)
  for (int t = wv; t < 64; t += 8) {
    const float* xp = x + (size_t)st_s[t] * CC;
    const float v0 = xp[lane];
    const float v1 = (lane < 32) ? xp[64 + lane] : 0.f;
    float s = v0 + v1, s2 = v0 * v0 + v1 * v1;
    #pragma unroll
    for (int off = 32; off; off >>= 1) {
      s  += __shfl_xor(s,  off);
      s2 += __shfl_xor(s2, off);
    }
    const float mean = s * (1.f / 96.f);
    const float var  = s2 * (1.f / 96.f) - mean * mean;
    const float inv  = rsqrtf(var + 1e-5f);
    a[t][lane] = f2bf((v0 - mean) * inv * n1s[lane] + n1b[lane]);
    if (lane < 32)
      a[t][64 + lane] = f2bf((v1 - mean) * inv * n1s[64 + lane] + n1b[64 + lane]);
  }
  __syncthreads();

  // phase 2: qkv MFMA — 72 output tiles (4 row x 18 col) over 8 waves
  for (int tt = wv; tt < 72; tt += 8) {
    const int rt = tt / 18, ct = tt % 18;
    const int n0g = ct * 16;
    const unsigned short* bp = wq_ld + (size_t)(n0g + row) * 96 + ko;
    const float bz = qkvb[n0g + cc];
    f32x4 acc = {0.f, 0.f, 0.f, 0.f};
    const unsigned short* ap = &a[rt * 16 + row][ko];
    #pragma unroll
    for (int k0 = 0; k0 < 96; k0 += 32) {
      const short8 af = *(const short8*)(ap + k0);
      const short8 bf = *(const short8*)(bp + k0);
      acc = __builtin_amdgcn_mfma_f32_16x16x32_bf16(af, bf, acc, 0, 0, 0);
    }
    #pragma unroll
    for (int r = 0; r < 4; ++r) {
      const int tok = rt * 16 + cr0 + r;
      const float v = acc[r] + bz;
      if (ct < 6)       qt[tok][ct * 16 + cc] = f2bf(v);
      else if (ct < 12) kk[tok][(ct - 6) * 16 + cc] = f2bf(v);
      else              vvT[((ct - 12) * 16 + cc) * 72 + tok] = f2bf(v);
    }
  }
  __syncthreads();

  // phase 3: MFMA attention — waves 0..5 (wave = head); 6,7 idle
  if (wv < 6) {
    const int head = wv;
    const int g  = lane >> 4;
    const bool lo = (lane < 32);
    const float* bias_h = rpbt_ld + head * 225;
    unsigned short* pb = vvT + head * (16 * 72);   // overlay own head's vvT rows
    const short8 z8 = {0, 0, 0, 0, 0, 0, 0, 0};
    short8 vf0, vf1;
    {
      const unsigned short* vp = vvT + (size_t)(head * 16 + cc) * 72 + g * 8;
      vf0 = *(const short8*)(vp);
      vf1 = *(const short8*)(vp + 32);
    }
    #pragma unroll
    for (int qtile = 0; qtile < 4; ++qtile) {
      short8 af = z8;
      if (lo) af = *(const short8*)&qt[qtile * 16 + cc][head * 16 + g * 8];
      f32x4 sa[4];
      #pragma unroll
      for (int kt = 0; kt < 4; ++kt) {
        short8 bf = z8;
        if (lo) bf = *(const short8*)&kk[kt * 16 + cc][head * 16 + g * 8];
        const f32x4 zero = {0.f, 0.f, 0.f, 0.f};
        sa[kt] = __builtin_amdgcn_mfma_f32_16x16x32_bf16(af, bf, zero, 0, 0, 0);
      }
      float p[4][4];
      #pragma unroll
      for (int r = 0; r < 4; ++r) {
        const int i = qtile * 16 + g * 4 + r;
        const int ih = i >> 3, iw = i & 7;
        const int ri = reg_s[i];
        float mx = -1e30f;
        #pragma unroll
        for (int kt = 0; kt < 4; ++kt) {
          const int j = kt * 16 + cc;
          const int idx = (ih - (j >> 3) + 7) * 15 + (iw - (j & 7) + 7);
          float v = sa[kt][r] * 0.25f + bias_h[idx];
          if (shift && reg_s[j] != ri) v -= 100.f;
          p[kt][r] = v;
          mx = fmaxf(mx, v);
        }
        mx = fmaxf(mx, __shfl_xor(mx, 1));
        mx = fmaxf(mx, __shfl_xor(mx, 2));
        mx = fmaxf(mx, __shfl_xor(mx, 4));
        mx = fmaxf(mx, __shfl_xor(mx, 8));
        float sum = 0.f;
        #pragma unroll
        for (int kt = 0; kt < 4; ++kt) {
          p[kt][r] = __expf(p[kt][r] - mx);
          sum += p[kt][r];
        }
        sum += __shfl_xor(sum, 1);
        sum += __shfl_xor(sum, 2);
        sum += __shfl_xor(sum, 4);
        sum += __shfl_xor(sum, 8);
        const float is = 1.f / sum;
        #pragma unroll
        for (int kt = 0; kt < 4; ++kt)
          pb[(g * 4 + r) * 72 + kt * 16 + cc] = f2bf(p[kt][r] * is);
      }
      f32x4 oa = {0.f, 0.f, 0.f, 0.f};
      {
        const unsigned short* pp = pb + cc * 72 + g * 8;
        const short8 pf0 = *(const short8*)(pp);
        const short8 pf1 = *(const short8*)(pp + 32);
        oa = __builtin_amdgcn_mfma_f32_16x16x32_bf16(pf0, vf0, oa, 0, 0, 0);
        oa = __builtin_amdgcn_mfma_f32_16x16x32_bf16(pf1, vf1, oa, 0, 0, 0);
      }
      #pragma unroll
      for (int r = 0; r < 4; ++r)
        a[qtile * 16 + g * 4 + r][head * 16 + cc] = f2bf(oa[r]);
    }
  }
  __syncthreads();

  // phase 4: proj MFMA; xacc = x_old + proj + bias — 24 tiles over 8 waves
  for (int tt = wv; tt < 24; tt += 8) {
    const int rt = tt / 6, ct = tt % 6;
    const int n0 = ct * 16;
    const unsigned short* bp = wp_ld + (size_t)(n0 + row) * 96 + ko;
    const float bz = projb[n0 + cc];
    f32x4 acc = {0.f, 0.f, 0.f, 0.f};
    const unsigned short* ap = &a[rt * 16 + row][ko];
    #pragma unroll
    for (int k0 = 0; k0 < 96; k0 += 32) {
      const short8 af = *(const short8*)(ap + k0);
      const short8 bf = *(const short8*)(bp + k0);
      acc = __builtin_amdgcn_mfma_f32_16x16x32_bf16(af, bf, acc, 0, 0, 0);
    }
    #pragma unroll
    for (int r = 0; r < 4; ++r) {
      const int tok = rt * 16 + cr0 + r;
      const float xo = x[(size_t)st_s[tok] * CC + n0 + cc];
      xacc[tok][n0 + cc] = xo + acc[r] + bz;
    }
  }
  __syncthreads();

  // phase 5: LN2 from xacc -> a
  for (int t = wv; t < 64; t += 8) {
    const float v0 = xacc[t][lane];
    const float v1 = (lane < 32) ? xacc[t][64 + lane] : 0.f;
    float s = v0 + v1, s2 = v0 * v0 + v1 * v1;
    #pragma unroll
    for (int off = 32; off; off >>= 1) {
      s  += __shfl_xor(s,  off);
      s2 += __shfl_xor(s2, off);
    }
    const float mean = s * (1.f / 96.f);
    const float var  = s2 * (1.f / 96.f) - mean * mean;
    const float inv  = rsqrtf(var + 1e-5f);
    a[t][lane] = f2bf((v0 - mean) * inv * n2s[lane] + n2b[lane]);
    if (lane < 32)
      a[t][64 + lane] = f2bf((v1 - mean) * inv * n2s[64 + lane] + n2b[64 + lane]);
  }
  __syncthreads();

  // phase 6: MLP in 4 K-passes of 96 hidden cols; fc2 tiles fixed per wave
  f32x4 acc2[3];
  #pragma unroll
  for (int i = 0; i < 3; ++i) acc2[i] = (f32x4){0.f, 0.f, 0.f, 0.f};
  for (int p = 0; p < 4; ++p) {
    for (int tt = wv; tt < 24; tt += 8) {
      const int rt = tt / 6, ct = tt % 6;
      const int n0g = p * 96 + ct * 16;
      const unsigned short* bp = w1_ld + (size_t)(n0g + row) * 96 + ko;
      const float bz = f1b[n0g + cc];
      f32x4 acc = {0.f, 0.f, 0.f, 0.f};
      const unsigned short* ap = &a[rt * 16 + row][ko];
      #pragma unroll
      for (int k0 = 0; k0 < 96; k0 += 32) {
        const short8 af = *(const short8*)(ap + k0);
        const short8 bf = *(const short8*)(bp + k0);
        acc = __builtin_amdgcn_mfma_f32_16x16x32_bf16(af, bf, acc, 0, 0, 0);
      }
      #pragma unroll
      for (int r = 0; r < 4; ++r) {
        float v = acc[r] + bz;
        v = 0.5f * v * (1.f + erff(v * 0.70710678118f));
        hbuf[rt * 16 + cr0 + r][ct * 16 + cc] = f2bf(v);
      }
    }
    __syncthreads();
    #pragma unroll
    for (int i = 0; i < 3; ++i) {
      const int tt2 = wv * 3 + i;
      const int rt = tt2 / 6, ct = tt2 % 6;
      const unsigned short* bp = w2_ld + (size_t)(ct * 16 + row) * 384 + p * 96 + ko;
      const unsigned short* ap = &hbuf[rt * 16 + row][ko];
      #pragma unroll
      for (int k0 = 0; k0 < 96; k0 += 32) {
        const short8 af = *(const short8*)(ap + k0);
        const short8 bf = *(const short8*)(bp + k0);
        acc2[i] = __builtin_amdgcn_mfma_f32_16x16x32_bf16(af, bf, acc2[i], 0, 0, 0);
      }
    }
    __syncthreads();
  }

  // phase 7: final write x = xacc + fc2 + bias
  #pragma unroll
  for (int i = 0; i < 3; ++i) {
    const int tt2 = wv * 3 + i;
    const int rt = tt2 / 6, ct = tt2 % 6;
    const int n0 = ct * 16;
    const float bz = f2b[n0 + cc];
    #pragma unroll
    for (int r = 0; r < 4; ++r) {
      const int tok = rt * 16 + cr0 + r;
      x[(size_t)st_s[tok] * CC + n0 + cc] = xacc[tok][n0 + cc] + acc2[i][r] + bz;
    }
  }
}

// ---------------------------------------------------------------- copy
__global__ __launch_bounds__(256) void copy_kernel(
    float* __restrict__ dst, const float* __restrict__ src)
{
  const int idx = blockIdx.x * 256 + threadIdx.x;
  dst[idx] = src[idx];
}

// ---------------------------------------------------------------- conv 3x3 96->96, MFMA implicit GEMM, optional dual write
__global__ __launch_bounds__(256) void conv96m_kernel(
    const float* __restrict__ x, const unsigned short* __restrict__ wt,
    const float* __restrict__ bias, const float* resid, float* out, float* out2)
{
  const int blk = blockIdx.x;
  const int b = blk >> 4, th = (blk >> 2) & 3, tw = blk & 3;
  const int h0 = th * 8, w0 = tw * 8;
  __shared__ unsigned short patch[100][104];
  for (int idx = threadIdx.x; idx < 100 * 24; idx += 256) {
    const int pp = idx / 24, c4 = (idx % 24) * 4;
    const int ph = pp / 10, pw = pp % 10;
    const int hh = h0 + ph - 1, ww = w0 + pw - 1;
    float4 v = {0.f, 0.f, 0.f, 0.f};
    if ((unsigned)hh < 32u && (unsigned)ww < 32u)
      v = *(const float4*)&x[(((size_t)b * 32 + hh) * 32 + ww) * 96 + c4];
    ushort4v o;
    o.x = f2bf(v.x); o.y = f2bf(v.y); o.z = f2bf(v.z); o.w = f2bf(v.w);
    *(ushort4v*)&patch[pp][c4] = o;
  }
  __syncthreads();
  const int wv = threadIdx.x >> 6, lane = threadIdx.x & 63;
  const int m0 = wv * 16;
  const int arow = lane & 15;
  const int ko  = (lane >> 4) * 8;
  const int px = m0 + arow;
  const int ph_ = px >> 3, pw_ = px & 7;
  f32x4 acc[6];
  #pragma unroll
  for (int i = 0; i < 6; ++i) acc[i] = (f32x4){0.f, 0.f, 0.f, 0.f};
  #pragma unroll
  for (int kh = 0; kh < 3; ++kh)
    #pragma unroll
    for (int kw = 0; kw < 3; ++kw) {
      const unsigned short* wbase = wt + (size_t)(kh * 3 + kw) * 9216;
      const unsigned short* prow = &patch[(ph_ + kh) * 10 + (pw_ + kw)][ko];
      #pragma unroll
      for (int k0 = 0; k0 < 96; k0 += 32) {
        const short8 af = *(const short8*)(prow + k0);
        #pragma unroll
        for (int nt = 0; nt < 6; ++nt) {
          const short8 bf = *(const short8*)(wbase + (size_t)(nt * 16 + arow) * 96 + ko + k0);
          acc[nt] = __builtin_amdgcn_mfma_f32_16x16x32_bf16(af, bf, acc[nt], 0, 0, 0);
        }
      }
    }
  const int cc = lane & 15;
  const int cr0 = (lane >> 4) * 4;
  #pragma unroll
  for (int nt = 0; nt < 6; ++nt) {
    const int oc = nt * 16 + cc;
    const float bz = bias[oc];
    #pragma unroll
    for (int r = 0; r < 4; ++r) {
      const int p = m0 + cr0 + r;
      const int h = p >> 3, w = p & 7;
      const size_t t = (((size_t)b * 32 + h0 + h) * 32 + (w0 + w));
      float v = acc[nt][r] + bz;
      if (resid) v += resid[t * 96 + oc];
      out[t * 96 + oc] = v;
      if (out2) out2[t * 96 + oc] = v;
    }
  }
}

// ---------------------------------------------------------------- conv stem 4->96
__global__ __launch_bounds__(256) void conv_first_kernel(
    const float* __restrict__ es, const float* __restrict__ jp,
    const float* __restrict__ wgt, const float* __restrict__ bias,
    float* __restrict__ xf)
{
  const int idx = blockIdx.x * 256 + threadIdx.x;
  const int oc = idx % 96;
  const int pos = idx / 96;
  const int w = pos % 32, hp = (pos / 32) % 32, b = pos / 1024;
  float acc = bias[oc];
  for (int kh = 0; kh < 3; ++kh) {
    const int hh = hp + kh - 1;
    if ((unsigned)hh >= 32u) continue;
    for (int kw = 0; kw < 3; ++kw) {
      const int ww = w + kw - 1;
      if ((unsigned)ww >= 32u) continue;
      const size_t sp = ((size_t)b * 2 * 32 + hh) * 32 + ww;
      const float i0 = es[sp];
      const float i1 = es[sp + 1024];
      const float i2 = jp[sp];
      const float i3 = jp[sp + 1024];
      const float* wr = wgt + (size_t)((kh * 3 + kw) * 4) * 96 + oc;
      acc = fmaf(i0, wr[0], acc);
      acc = fmaf(i1, wr[96], acc);
      acc = fmaf(i2, wr[192], acc);
      acc = fmaf(i3, wr[288], acc);
    }
  }
  xf[idx] = acc;
}

// ---------------------------------------------------------------- conv tail 96->2
__global__ __launch_bounds__(256) void conv_last_kernel(
    const float* __restrict__ res, const float* __restrict__ wgt,
    const float* __restrict__ bias, float* __restrict__ out)
{
  const int idx = blockIdx.x * 256 + threadIdx.x;
  const int oc = idx % 2;
  const int pos = idx / 2;
  const int w = pos % 32, hp = (pos / 32) % 32, b = pos / 1024;
  float acc = bias[oc];
  for (int kh = 0; kh < 3; ++kh) {
    const int hh = hp + kh - 1;
    if ((unsigned)hh >= 32u) continue;
    for (int kw = 0; kw < 3; ++kw) {
      const int ww = w + kw - 1;
      if ((unsigned)ww >= 32u) continue;
      const float* pr = res + (((size_t)b * 32 + hh) * 32 + ww) * 96;
      const float* wr = wgt + (size_t)((kh * 3 + kw) * 96) * 2 + oc;
      #pragma unroll 8
      for (int ic = 0; ic < 96; ++ic)
        acc = fmaf(pr[ic], wr[ic * 2], acc);
    }
  }
  out[(((size_t)b * 2 + oc) * 32 + hp) * 32 + w] = acc;
}

// ---------------------------------------------------------------- host
extern "C" void kernel_launch(void* const* d_in, const int* in_sizes, int n_in,
                              void* d_out, int out_size, void* d_ws, size_t ws_size,
                              hipStream_t stream)
{
  const int fill_grid = (out_size + 255) / 256;

  if (n_in != 27) {
    fill_kernel<<<fill_grid, 256, 0, stream>>>((float*)d_out, 200.0f + (float)n_in, out_size);
    return;
  }
  static const int expected_sizes[27] = {
    131072, 131072, 3456, 96, 96, 96, 2304, 2304, 663552, 6912,
    221184, 2304, 32400, 2304, 2304, 884736, 9216, 884736, 2304,
    331776, 384, 96, 96, 82944, 96, 1728, 2
  };
  for (int i = 0; i < 27; ++i) {
    if (in_sizes[i] != expected_sizes[i]) {
      fill_kernel<<<fill_grid, 256, 0, stream>>>((float*)d_out, 300.0f + (float)i, out_size);
      return;
    }
  }
  if (out_size != 131072) {
    fill_kernel<<<fill_grid, 256, 0, stream>>>((float*)d_out, 400.0f, out_size);
    return;
  }
  const uintptr_t raw = (uintptr_t)d_ws;
  const uintptr_t alignedp = (raw + 255) & ~(uintptr_t)255;
  const size_t ws_avail_bytes = (ws_size > (alignedp - raw)) ? ws_size - (alignedp - raw) : 0;
  const size_t avail = ws_avail_bytes / 4;   // floats
  const size_t WBUF_F = 1534464 + 32400;     // bf16 weights + rpbT(f32), float units
  if (avail < 2 * TC + WBUF_F) {
    fill_kernel<<<fill_grid, 256, 0, stream>>>((float*)d_out,
        100.0f + (float)(ws_size >> 20), out_size);
    return;
  }
  const bool rot = (avail >= 3 * TC + WBUF_F);   // 3-buffer rotation (no copies)

  const float* es      = (const float*)d_in[0];
  const float* jp      = (const float*)d_in[1];
  const float* cf_w    = (const float*)d_in[2];
  const float* cf_b    = (const float*)d_in[3];
  const float* pe_s    = (const float*)d_in[4];
  const float* pe_b    = (const float*)d_in[5];
  const float* n1_s    = (const float*)d_in[6];
  const float* n1_b    = (const float*)d_in[7];
  const float* qkv_w   = (const float*)d_in[8];
  const float* qkv_b   = (const float*)d_in[9];
  const float* proj_w  = (const float*)d_in[10];
  const float* proj_b  = (const float*)d_in[11];
  const float* rpb     = (const float*)d_in[12];
  const float* n2_s    = (const float*)d_in[13];
  const float* n2_b    = (const float*)d_in[14];
  const float* fc1_w   = (const float*)d_in[15];
  const float* fc1_b   = (const float*)d_in[16];
  const float* fc2_w   = (const float*)d_in[17];
  const float* fc2_b   = (const float*)d_in[18];
  const float* rstb_w  = (const float*)d_in[19];
  const float* rstb_b  = (const float*)d_in[20];
  const float* nf_s    = (const float*)d_in[21];
  const float* nf_b    = (const float*)d_in[22];
  const float* body_w  = (const float*)d_in[23];
  const float* body_b  = (const float*)d_in[24];
  const float* last_w  = (const float*)d_in[25];
  const float* last_b  = (const float*)d_in[26];

  float* base = (float*)alignedp;
  float* x  = base;
  float* r  = base + TC;
  float* sp = rot ? base + 2 * TC : nullptr;
  unsigned short* wq  = (unsigned short*)(base + (rot ? 3 : 2) * TC);
  unsigned short* wpj = wq + 663552;
  unsigned short* w1  = wpj + 221184;
  unsigned short* w2  = w1 + 884736;
  unsigned short* wcr = w2 + 884736;
  unsigned short* wcb = wcr + 331776;
  float* rpbt = (float*)(wcb + 82944);          // [24][6][225] f32

  const int grid_tc = (int)(TC / 256);
  const int grid_lf = T_TOK / 4;
  const int nwin = T_TOK / 64;                       // 1024

  // weight convert+transpose
  wconv_kernel<<<dim3((96 * 288 + 255) / 256, 24), 256, 0, stream>>>(qkv_w, wq, 96, 288);
  wconv_kernel<<<dim3((96 * 96 + 255) / 256, 24), 256, 0, stream>>>(proj_w, wpj, 96, 96);
  wconv_kernel<<<dim3((96 * 384 + 255) / 256, 24), 256, 0, stream>>>(fc1_w, w1, 96, 384);
  wconv_kernel<<<dim3((384 * 96 + 255) / 256, 24), 256, 0, stream>>>(fc2_w, w2, 384, 96);
  wconv_conv_kernel<<<(331776 + 255) / 256, 256, 0, stream>>>(rstb_w, wcr, 331776);
  wconv_conv_kernel<<<(82944 + 255) / 256, 256, 0, stream>>>(body_w, wcb, 82944);
  rpbt_kernel<<<(24 * 1350 + 255) / 256, 256, 0, stream>>>(rpb, rpbt);

  // stem
  conv_first_kernel<<<grid_tc, 256, 0, stream>>>(es, jp, cf_w, cf_b, x);
  ln_fp32_kernel<<<grid_lf, 256, 0, stream>>>(x, pe_s, pe_b, x, rot ? r : nullptr);

  float* xb = x;
  float* rb = r;
  float* sb = sp;
  for (int l = 0; l < NL; ++l) {
    if (!rot) copy_kernel<<<grid_tc, 256, 0, stream>>>(rb, xb);
    for (int d = 0; d < ND; ++d) {
      const int ld = l * ND + d;
      const int shift = (d & 1) ? 4 : 0;
      swin_block_fused<<<nwin, 512, 0, stream>>>(
          xb, n1_s + ld * CC, n1_b + ld * CC,
          wq + (size_t)ld * 288 * 96, qkv_b + (size_t)ld * 288,
          rpbt + (size_t)ld * 1350,
          wpj + (size_t)ld * 96 * 96, proj_b + (size_t)ld * 96,
          n2_s + ld * CC, n2_b + ld * CC,
          w1 + (size_t)ld * 384 * 96, fc1_b + (size_t)ld * 384,
          w2 + (size_t)ld * 96 * 384, fc2_b + (size_t)ld * 96, shift);
    }
    if (rot) {
      conv96m_kernel<<<1024, 256, 0, stream>>>(xb, wcr + (size_t)l * 9 * 9216,
                                               rstb_b + (size_t)l * CC, rb, rb, sb);
      float* t = xb; xb = sb; sb = t;
    } else {
      conv96m_kernel<<<1024, 256, 0, stream>>>(xb, wcr + (size_t)l * 9 * 9216,
                                               rstb_b + (size_t)l * CC, rb, rb, nullptr);
      float* t = xb; xb = rb; rb = t;
    }
  }
  // tail
  ln_fp32_kernel<<<grid_lf, 256, 0, stream>>>(xb, nf_s, nf_b, rb, nullptr);
  conv_first_kernel<<<grid_tc, 256, 0, stream>>>(es, jp, cf_w, cf_b, xb);
  conv96m_kernel<<<1024, 256, 0, stream>>>(rb, wcb, body_b, xb, xb, nullptr);
  conv_last_kernel<<<(BB * 32 * 32 * 2) / 256, 256, 0, stream>>>(xb, last_w, last_b, (float*)d_out);
}